// Round 2
// 547.543 us; speedup vs baseline: 1.0767x; 1.0767x over previous
//
#include <hip/hip_runtime.h>

// ---------------------------------------------------------------------------
// VeRA Linear: y = x @ (W + 4*diag(b) B diag(d) A)^T + bias
// T=8192, IN=OUT=4096, R=256, fp32 in/out.
// R5 (= R4 resubmit after container infra failure, + hardened waits):
// 256x256-tile 8-wave deep-pipelined GEMM (T3+T4+T5+T1):
//   - BK=64, double-buffered 128KB LDS, k-half (32-col) staging units
//   - counted s_waitcnt vmcnt(8) lgkmcnt(0) before each barrier (never
//     vmcnt(0) in steady state): prefetch loads stay in flight across
//     barriers; 2 barriers per 64 wave-MFMAs (vs 2 per 16 in the R3
//     128^2 structure -> ~900 TF ceiling)
//   - setprio(1) around each 16-MFMA cluster
//   - XCD-bijective block swizzle, column-major tile order (B-panel 2MB/L2)
//   - conflict-free LDS: linear global_load_lds dest + inverse-swizzled
//     global source; chunk q of row r at slot q^((r>>1)&3) within [kh][256][32]
// Region-safety: every stage targets LDS whose last reader drained (lgkmcnt
// folded into the pre-barrier wait) before the barrier preceding the issue.
// ---------------------------------------------------------------------------

typedef __attribute__((ext_vector_type(8))) short short8;   // 8 bf16 = 4 VGPRs
typedef __attribute__((ext_vector_type(4))) float f32x4;    // MFMA acc

__device__ __forceinline__ unsigned short f2bf(float f) {
  union { float f; unsigned int u; } c; c.f = f;
  unsigned int u = c.u;
  unsigned int r = (u + 0x7fffu + ((u >> 16) & 1u)) >> 16;  // RNE, finite inputs
  return (unsigned short)r;
}

__device__ __forceinline__ void gl2lds16(const unsigned short* g, unsigned short* l) {
  __builtin_amdgcn_global_load_lds(
      (const __attribute__((address_space(1))) unsigned int*)g,
      (__attribute__((address_space(3))) unsigned int*)l, 16, 0, 0);
}

// Merged prep: blocks [0,8192) cvt x->bf16 (4 float4/thread);
// [8192,12288) Bd; [12288,13312) A^T.
__global__ __launch_bounds__(256) void k_pre(const float* __restrict__ x,
                                             unsigned short* __restrict__ xb,
                                             const float* __restrict__ Bv,
                                             const float* __restrict__ Av,
                                             const float* __restrict__ dv,
                                             const float* __restrict__ bv,
                                             unsigned short* __restrict__ Bd,
                                             unsigned short* __restrict__ AbT) {
  __shared__ float tl[32][33];
  const int blk = blockIdx.x;
  const int tid = threadIdx.x;
  if (blk < 8192) {
#pragma unroll
    for (int s = 0; s < 4; ++s) {
      int i = blk * 1024 + s * 256 + tid;
      const float4 v = ((const float4*)x)[i];
      union { unsigned short u[4]; unsigned long long ll; } o;
      o.u[0] = f2bf(v.x); o.u[1] = f2bf(v.y); o.u[2] = f2bf(v.z); o.u[3] = f2bf(v.w);
      ((unsigned long long*)xb)[i] = o.ll;
    }
  } else if (blk < 12288) {
    // Bd[o][r] = bf16(4 * b[o] * B[o][r] * d[r])
    int idx = (blk - 8192) * 256 + tid;
    int o = idx >> 8, r = idx & 255;
    Bd[idx] = f2bf(4.0f * bv[o] * Bv[idx] * dv[r]);
  } else {
    // AbT[i][r] = bf16(A[r][i]) via padded LDS tile (coalesced both sides)
    int blk2 = blk - 12288;           // 1024 blocks
    int ti = blk2 >> 3;               // i-block, 0..127
    int tr = blk2 & 7;                // r-block, 0..7
#pragma unroll
    for (int s = 0; s < 4; ++s) {
      int r = tr * 32 + s * 8 + (tid >> 5);
      int i = ti * 32 + (tid & 31);
      tl[s * 8 + (tid >> 5)][tid & 31] = Av[(size_t)r * 4096 + i];
    }
    __syncthreads();
#pragma unroll
    for (int s = 0; s < 4; ++s) {
      int iloc = s * 8 + (tid >> 5);
      int rloc = tid & 31;
      AbT[(size_t)(ti * 32 + iloc) * 256 + tr * 32 + rloc] = f2bf(tl[rloc][iloc]);
    }
  }
}

// ---------------------------------------------------------------------------
// C[m][n] = sum_k Amat[m][k]*Bmat[n][k]  (row-major, K contiguous, K%128==0)
// FOLD=1: outB[m*N+n] = bf16(extra[m*N+n] + acc)   (extra = base W)
// FOLD=0: outF[m*N+n] = acc + extra[n]             (extra = bias)
//
// 256x256 block, 512 thr (8 waves, 2M x 4N), per-wave 128x64 output.
// LDS planes: [buf(2)][khalf(2)][256 rows][32 cols] bf16 per matrix = 128KB.
// K-tile t (buf t&1), 4 phases:
//   P1: vmcnt(8)+lgkm(0); barrier; issue A-k1(t+1); read Bk0+A(mh0,k0); 16 MFMA
//   P2:                            issue B-k1(t+1); read A(mh1,k0);     16 MFMA
//   P3: vmcnt(8)+lgkm(0); barrier; issue A-k0(t+2); read Bk1+A(mh0,k1); 16 MFMA
//   P4:                            issue B-k0(t+2); read A(mh1,k1);     16 MFMA
// Steady state leaves 8 loads (2 units) in flight across every wait.
// In-flight trace (verified): prologue 12; each wait drains exactly the
// 4 oldest = the half-buffer read right after the barrier.
// ---------------------------------------------------------------------------
template <int FOLD>
__global__ __launch_bounds__(512, 2) void gemm256(const unsigned short* __restrict__ Amat,
                                                  const unsigned short* __restrict__ Bmat,
                                                  int K, int N, int NBY,
                                                  const float* __restrict__ extra,
                                                  float* __restrict__ outF,
                                                  unsigned short* __restrict__ outB) {
  __shared__ __align__(16) unsigned short As[2 * 2 * 8192];   // 64KB
  __shared__ __align__(16) unsigned short Bs[2 * 2 * 8192];   // 64KB

  const int tid  = threadIdx.x;
  const int lane = tid & 63;
  const int wave = tid >> 6;      // 0..7
  const int wm   = wave >> 2;     // 0..1  (M half)
  const int wn   = wave & 3;      // 0..3  (N quarter)
  const int quad = lane >> 4;     // 0..3
  const int m16  = lane & 15;
  const int qsl  = quad ^ ((m16 >> 1) & 3);   // de-swizzled chunk slot

  // XCD-bijective remap (gridDim.x % 8 == 0), column-major tile order:
  // each XCD chunk walks M-blocks within a 256-col B-panel (2MB, L2-fit).
  const int nwg  = gridDim.x;
  const int cpx  = nwg >> 3;
  const int wgid = (blockIdx.x & 7) * cpx + (blockIdx.x >> 3);
  const int by   = wgid % NBY;
  const int bx   = wgid / NBY;
  const int blockM = by * 256;
  const int blockN = bx * 256;

  // Staging: inst j covers rows [j*128, j*128+128); thread: row r=j*128+(tid>>2),
  // dest slot c=tid&3 (16B chunks), source chunk q=c^((r>>1)&3)=c^((tid>>3)&3).
  // Dest is linear (base + tid*16B) as global_load_lds requires.
  const int srow = tid >> 2;
  const int sq8  = ((tid & 3) ^ ((tid >> 3) & 3)) * 8;
  const size_t aB0 = (size_t)(blockM + srow) * K + sq8;
  const size_t aB1 = aB0 + (size_t)128 * K;
  const size_t bB0 = (size_t)(blockN + srow) * K + sq8;
  const size_t bB1 = bB0 + (size_t)128 * K;

  const short8* Asv = (const short8*)As;
  const short8* Bsv = (const short8*)Bs;
  // read bases (short8 units within an 8192-elem plane = 1024 units)
  const int aRd = wm * 512 + m16 * 4 + qsl;   // + mh*256 + mt*64 + plane*1024
  const int bRd = wn * 256 + m16 * 4 + qsl;   // + nt*64           + plane*1024

  f32x4 acc[8][4];
#pragma unroll
  for (int i = 0; i < 8; ++i)
#pragma unroll
    for (int j = 0; j < 4; ++j) acc[i][j] = (f32x4){0.f, 0.f, 0.f, 0.f};

  short8 afr[4], bfr[4];

// Combined wait: counted vmcnt keeps prefetch in flight; lgkmcnt(0) is
// ~free (ds_reads already consumed by MFMAs) and guarantees no ds op is
// pending across the barrier regardless of compiler wait placement.
#define WAITV(n) asm volatile("s_waitcnt vmcnt(" #n ") lgkmcnt(0)" ::: "memory")

#define ISSUE_A(bufi, kh, koff) do {                                         \
    unsigned short* d_ = As + ((bufi) * 2 + (kh)) * 8192 + tid * 8;          \
    gl2lds16(Amat + aB0 + (koff) + (kh) * 32, d_);                           \
    gl2lds16(Amat + aB1 + (koff) + (kh) * 32, d_ + 4096);                    \
  } while (0)

#define ISSUE_B(bufi, kh, koff) do {                                         \
    unsigned short* d_ = Bs + ((bufi) * 2 + (kh)) * 8192 + tid * 8;          \
    gl2lds16(Bmat + bB0 + (koff) + (kh) * 32, d_);                           \
    gl2lds16(Bmat + bB1 + (koff) + (kh) * 32, d_ + 4096);                    \
  } while (0)

#define RD_B(Bb, h) do {                                                     \
    _Pragma("unroll") for (int nt = 0; nt < 4; ++nt)                         \
      bfr[nt] = Bsv[((Bb) * 2 + (h)) * 1024 + bRd + nt * 64];                \
  } while (0)

#define RD_A(Bb, h, mh) do {                                                 \
    _Pragma("unroll") for (int mt = 0; mt < 4; ++mt)                         \
      afr[mt] = Asv[((Bb) * 2 + (h)) * 1024 + aRd + (mh) * 256 + mt * 64];   \
  } while (0)

#define MM(mh) do {                                                          \
    __builtin_amdgcn_s_setprio(1);                                           \
    _Pragma("unroll") for (int mt = 0; mt < 4; ++mt)                         \
    _Pragma("unroll") for (int nt = 0; nt < 4; ++nt)                         \
      acc[(mh) * 4 + mt][nt] = __builtin_amdgcn_mfma_f32_16x16x32_bf16(      \
          afr[mt], bfr[nt], acc[(mh) * 4 + mt][nt], 0, 0, 0);                \
    __builtin_amdgcn_s_setprio(0);                                           \
  } while (0)

#define TILE(Bb, ko, W1, W3, I12, I34) do {                                  \
    WAITV(W1);                                                               \
    __builtin_amdgcn_s_barrier();                                            \
    if (I12) ISSUE_A((Bb) ^ 1, 1, (ko) + 64);                                \
    RD_B(Bb, 0); RD_A(Bb, 0, 0); MM(0);                                      \
    if (I12) ISSUE_B((Bb) ^ 1, 1, (ko) + 64);                                \
    RD_A(Bb, 0, 1); MM(1);                                                   \
    WAITV(W3);                                                               \
    __builtin_amdgcn_s_barrier();                                            \
    if (I34) ISSUE_A(Bb, 0, (ko) + 128);                                     \
    RD_B(Bb, 1); RD_A(Bb, 1, 0); MM(0);                                      \
    if (I34) ISSUE_B(Bb, 0, (ko) + 128);                                     \
    RD_A(Bb, 1, 1); MM(1);                                                   \
  } while (0)

  // Prologue: tile0 {Ak0,Bk0,Ak1,Bk1} + tile1 {Ak0,Bk0} = 12 loads in flight.
  ISSUE_A(0, 0, (size_t)0);  ISSUE_B(0, 0, (size_t)0);
  ISSUE_A(0, 1, (size_t)0);  ISSUE_B(0, 1, (size_t)0);
  ISSUE_A(1, 0, (size_t)64); ISSUE_B(1, 0, (size_t)64);

  const int NT = K >> 6;      // K-tiles (NT even, >= 4 for both call sites)
  size_t ko = 0;
  for (int t = 0; t < NT - 2; t += 2) {
    TILE(0, ko, 8, 8, 1, 1);
    TILE(1, ko + 64, 8, 8, 1, 1);
    ko += 128;
  }
  TILE(0, ko, 8, 8, 1, 0);          // tile NT-2: stages (NT-1)'s k1 only
  TILE(1, ko + 64, 4, 0, 0, 0);     // tile NT-1: drain

#undef WAITV
#undef ISSUE_A
#undef ISSUE_B
#undef RD_B
#undef RD_A
#undef MM
#undef TILE

  // C/D layout: col = lane&15, row = quad*4 + reg  [verified m89/m91]
#pragma unroll
  for (int mt = 0; mt < 8; ++mt) {
    const int row0 = blockM + wm * 128 + mt * 16 + quad * 4;
#pragma unroll
    for (int nt = 0; nt < 4; ++nt) {
      const int col = blockN + wn * 64 + nt * 16 + m16;
      f32x4 v = acc[mt][nt];
      if (FOLD) {
#pragma unroll
        for (int r = 0; r < 4; ++r) {
          size_t o = (size_t)(row0 + r) * N + col;
          outB[o] = f2bf(extra[o] + v[r]);
        }
      } else {
        const float bb = extra[col];
#pragma unroll
        for (int r = 0; r < 4; ++r) {
          size_t o = (size_t)(row0 + r) * N + col;
          outF[o] = v[r] + bb;
        }
      }
    }
  }
}

extern "C" void kernel_launch(void* const* d_in, const int* in_sizes, int n_in,
                              void* d_out, int out_size, void* d_ws, size_t ws_size,
                              hipStream_t stream) {
  const float* x    = (const float*)d_in[0];  // (8192, 4096)
  const float* W    = (const float*)d_in[1];  // (4096, 4096)
  const float* bias = (const float*)d_in[2];  // (4096,)
  const float* A    = (const float*)d_in[3];  // (256, 4096)
  const float* B    = (const float*)d_in[4];  // (4096, 256)
  const float* dv   = (const float*)d_in[5];  // (256,)
  const float* bv   = (const float*)d_in[6];  // (4096,)
  float* out = (float*)d_out;                 // (8192, 4096)

  char* ws = (char*)d_ws;
  unsigned short* xb  = (unsigned short*)ws;                        // 64MB x bf16
  unsigned short* Wc  = (unsigned short*)(ws + (size_t)(64 << 20)); // 32MB W+delta bf16
  unsigned short* Bd  = (unsigned short*)(ws + (size_t)(96 << 20)); // 2MB
  unsigned short* AbT = (unsigned short*)(ws + (size_t)(98 << 20)); // 2MB

  // 1. cvt + Bd + A^T in one launch
  hipLaunchKernelGGL(k_pre, dim3(13312), dim3(256), 0, stream,
                     x, xb, B, A, dv, bv, Bd, AbT);
  // 2. Wc = bf16(W + Bd @ AbT^T)   M=N=4096, K=256  (16x16 tiles, 256 blocks)
  hipLaunchKernelGGL((gemm256<1>), dim3(256), dim3(512), 0, stream,
                     Bd, AbT, 256, 4096, 16, W, (float*)nullptr, Wc);
  // 3. out = xb @ Wc^T + bias      M=8192, N=4096, K=4096  (16x32 tiles, 512 blocks)
  hipLaunchKernelGGL((gemm256<0>), dim3(512), dim3(512), 0, stream,
                     xb, Wc, 4096, 4096, 32, bias, out, (unsigned short*)nullptr);
}